// Round 1
// 2305.210 us; speedup vs baseline: 1.3596x; 1.3596x over previous
//
#include <hip/hip_runtime.h>
#include <hip/hip_bf16.h>

// Problem constants
#define N_NODES 20000
#define KK 20
#define DD 128
#define HH 4
#define DKK 32
#define EE 128
#define HIDD 512
#define RTOT (N_NODES * KK)   // 400000 rows

using bf16 = __hip_bfloat16;

typedef short s16x8 __attribute__((ext_vector_type(8)));   // 8 bf16 in 4 VGPRs
typedef float f32x4 __attribute__((ext_vector_type(4)));

__device__ __forceinline__ float geluf(float x) {
    return 0.5f * x * (1.0f + erff(x * 0.70710678118654752f));
}

__device__ __forceinline__ float wave_sum(float v) {
#pragma unroll
    for (int o = 32; o > 0; o >>= 1) v += __shfl_down(v, o);
    return __shfl(v, 0);
}

// ---------------------------------------------------------------------------
// Kernel 0: convert FFN weights to transposed bf16 [N][K] layout.
// w1t[n][k] = w1[k][n]  (512 x 128);  w2t[n][k] = w2[k][n]  (128 x 512)
// ---------------------------------------------------------------------------
__global__ __launch_bounds__(256)
void k0_conv(const float* __restrict__ w1, const float* __restrict__ w2,
             bf16* __restrict__ w1t, bf16* __restrict__ w2t)
{
    const int id = blockIdx.x * 256 + threadIdx.x;   // 0 .. 131071
    if (id < HIDD * DD) {
        const int n = id / DD, k = id % DD;          // w1t[n][k]
        w1t[id] = __float2bfloat16(w1[k * HIDD + n]);
    } else {
        const int j = id - HIDD * DD;                // w2t: n<128, k<512
        const int n = j / HIDD, k = j % HIDD;
        w2t[j] = __float2bfloat16(w2[k * DD + n]);
    }
}

// ---------------------------------------------------------------------------
// Kernel 0b: convert attention weights to transposed bf16 [n][k].
// aw = [wqT | wkT | wvT | wqsT | afwT], each 128x128: T[n][k] = W[k][n]
// ---------------------------------------------------------------------------
__global__ __launch_bounds__(256)
void k0b_conv(const float* __restrict__ wq, const float* __restrict__ wk,
              const float* __restrict__ wv, const float* __restrict__ wqs,
              const float* __restrict__ afw, bf16* __restrict__ aw)
{
    const int id = blockIdx.x * 256 + threadIdx.x;   // 0 .. 81919
    const int m = id >> 14;                          // matrix 0..4
    const int r = id & 16383;
    const int n = r >> 7, k = r & 127;
    const float* src = (m == 0) ? wq : (m == 1) ? wk : (m == 2) ? wv
                     : (m == 3) ? wqs : afw;
    aw[id] = __float2bfloat16(src[k * DD + n]);
}

// ---------------------------------------------------------------------------
// Kernel 1: z = node_h_src + gelu(edge_feat @ edge_fc_w + b) + cos((t_now-t)*freq+phase)
// ---------------------------------------------------------------------------
__global__ __launch_bounds__(1024)
void k1_msg(const float* __restrict__ nhs, const float* __restrict__ t,
            const float* __restrict__ t_now, const float* __restrict__ ef,
            const float* __restrict__ freq, const float* __restrict__ phase,
            const float* __restrict__ ew, const float* __restrict__ eb,
            bf16* __restrict__ z)
{
    __shared__ float efs[8][EE];
    const int tx = threadIdx.x;          // 0..127
    const int ty = threadIdx.y;          // 0..7
    const int row = blockIdx.x * 8 + ty;
    efs[ty][tx] = ef[row * EE + tx];
    __syncthreads();

    float acc = eb[tx];
#pragma unroll 4
    for (int e = 0; e < EE; e++)
        acc += efs[ty][e] * ew[e * DD + tx];

    const float tn = t_now[0];
    const float tenc = cosf((tn - t[row]) * freq[tx] + phase[tx]);
    const float zz = nhs[row * DD + tx] + geluf(acc) + tenc;
    z[row * DD + tx] = __float2bfloat16(zz);
}

// ---------------------------------------------------------------------------
// Kernel 2: per-node attention block, MFMA edition.
//   QKV projection + self_q: bf16 MFMA 16x16x32 (M=20 padded to 32; wave w
//     computes matrix w of {q,k,v,self_q}; self_q overwrites slot 19 of all).
//   scores/softmax/PV: fp32 VALU on LDS (rows padded +4 floats -> no 128-stride
//     bank conflicts).
//   attn_fc: bf16 MFMA from bf16 O tile; fused residual + rowwise LN.
// LDS (byte offsets, all 16-aligned):
//   zs  [32][136] bf16 @ 0      (8704)   z tile, rows 20..31 zeroed
//   qf  [20][132] f32  @ 8704   (10560)  -> obf [32][136] bf16 after scores
//   kf  [20][132] f32  @ 19264  (10560)  -> us  [20][132] f32  after scores
//   vf  [20][132] f32  @ 29824  (10560)
//   sc  [4][20][20] f32 @ 40384 (6400)
// total 46784 B -> 3 blocks/CU
// ---------------------------------------------------------------------------
__global__ __launch_bounds__(256)
void k2_attn(bf16* __restrict__ zx, const bf16* __restrict__ aw,
             const float* __restrict__ afb,
             const float* __restrict__ lng, const float* __restrict__ lnb)
{
    __shared__ __align__(16) char smem[46784];
    bf16  (*zs)[136]     = (bf16  (*)[136])(smem);
    float (*qf)[132]     = (float (*)[132])(smem + 8704);
    float (*kf)[132]     = (float (*)[132])(smem + 19264);
    float (*vf)[132]     = (float (*)[132])(smem + 29824);
    float (*sc)[KK][KK]  = (float (*)[KK][KK])(smem + 40384);
    bf16  (*obf)[136]    = (bf16  (*)[136])(smem + 8704);    // overlays qf
    float (*us)[132]     = (float (*)[132])(smem + 19264);   // overlays kf

    const int t    = threadIdx.x;
    const int wv4  = t >> 6;          // wave 0..3
    const int lane = t & 63;
    const int col  = lane & 15;
    const int quad = lane >> 4;       // 0..3
    const int node = blockIdx.x;
    bf16* zrow = zx + node * KK * DD;

    const uint4 z4 = make_uint4(0u, 0u, 0u, 0u);

    // --- stage z tile (20x128 bf16) + zero pad rows 20..31
    {
        const uint4* src = (const uint4*)zrow;            // 320 chunks of 16B
        for (int i = t; i < 320; i += 256) {
            const int r = i >> 4, c = (i & 15) * 8;
            *(uint4*)&zs[r][c] = src[i];
        }
        for (int i = t; i < 204; i += 256) {              // 12 rows x 17 uint4
            const int r = 20 + i / 17, c = (i % 17) * 8;
            *(uint4*)&zs[r][c] = z4;
        }
    }
    __syncthreads();

    // --- QKV (+self_q) via MFMA: wave wv4 computes z @ W[wv4]
    {
        const bf16* Wm = aw + wv4 * (DD * DD);
        f32x4 acc[2][8];
#pragma unroll
        for (int mt = 0; mt < 2; mt++)
#pragma unroll
            for (int nt = 0; nt < 8; nt++) acc[mt][nt] = (f32x4){0.f, 0.f, 0.f, 0.f};

#pragma unroll
        for (int kk = 0; kk < 4; kk++) {
            const int k0 = kk * 32 + quad * 8;
            const s16x8 a0 = *(const s16x8*)&zs[col][k0];
            const s16x8 a1 = *(const s16x8*)&zs[16 + col][k0];
#pragma unroll
            for (int nt = 0; nt < 8; nt++) {
                const s16x8 b = *(const s16x8*)&Wm[(nt * 16 + col) * DD + k0];
                acc[0][nt] = __builtin_amdgcn_mfma_f32_16x16x32_bf16(a0, b, acc[0][nt], 0, 0, 0);
                acc[1][nt] = __builtin_amdgcn_mfma_f32_16x16x32_bf16(a1, b, acc[1][nt], 0, 0, 0);
            }
        }

        if (wv4 < 3) {
            float (*dst)[132] = (wv4 == 0) ? qf : (wv4 == 1) ? kf : vf;
#pragma unroll
            for (int mt = 0; mt < 2; mt++)
#pragma unroll
                for (int nt = 0; nt < 8; nt++)
#pragma unroll
                    for (int r = 0; r < 4; r++) {
                        const int row = mt * 16 + quad * 4 + r;
                        if (row >= 19) continue;          // 19 comes from self_q; >=20 pad
                        dst[row][nt * 16 + col] = acc[mt][nt][r];
                    }
        } else if (quad == 0) {                           // wave 3: self_q = z[19] @ wqs
#pragma unroll
            for (int nt = 0; nt < 8; nt++) {
                const int n = nt * 16 + col;
                const float s = acc[1][nt][3];            // D row 19 (mt=1,quad=0,r=3)
                qf[19][n] = s; kf[19][n] = s; vf[19][n] = s;
            }
        }
    }
    __syncthreads();

    // --- scores (fp32 VALU; 132-float row stride -> bank-stagger 4)
    const float scale = 0.17677669529663687f;
    for (int idx = t; idx < HH * KK * KK; idx += 256) {
        const int h = idx / (KK * KK);
        const int rem = idx % (KK * KK);
        const int i = rem / KK, j = rem % KK;
        float s = 0.f;
#pragma unroll
        for (int d = 0; d < DKK; d++)
            s += qf[i][h * DKK + d] * kf[j][h * DKK + d];
        sc[h][i][j] = s * scale;
    }
    __syncthreads();

    // --- softmax over j<20
    if (t < HH * KK) {
        const int h = t / KK, i = t % KK;
        float m = -1e30f;
#pragma unroll
        for (int j = 0; j < KK; j++) m = fmaxf(m, sc[h][i][j]);
        float s = 0.f;
#pragma unroll
        for (int j = 0; j < KK; j++) { const float e = __expf(sc[h][i][j] - m); sc[h][i][j] = e; s += e; }
        const float inv = 1.0f / s;
#pragma unroll
        for (int j = 0; j < KK; j++) sc[h][i][j] *= inv;
    }
    __syncthreads();

    // --- PV (fp32 VALU) -> O tile in bf16 (obf overlays qf; qf is dead)
    for (int idx = t; idx < KK * DD; idx += 256) {
        const int i = idx / DD, c = idx % DD, h = c / DKK;
        float o = 0.f;
#pragma unroll
        for (int j = 0; j < KK; j++) o += sc[h][i][j] * vf[j][c];
        obf[i][c] = __float2bfloat16(o);
    }
    for (int i = t; i < 204; i += 256) {                  // zero obf rows 20..31
        const int r = 20 + i / 17, c = (i % 17) * 8;
        *(uint4*)&obf[r][c] = z4;
    }
    __syncthreads();

    // --- attn_fc via MFMA: X = O @ afwT + afb + z, then rowwise LN
    {
        const bf16* AF = aw + 4 * (DD * DD);
        f32x4 facc[2][2];
#pragma unroll
        for (int mt = 0; mt < 2; mt++)
#pragma unroll
            for (int nt = 0; nt < 2; nt++) facc[mt][nt] = (f32x4){0.f, 0.f, 0.f, 0.f};

#pragma unroll
        for (int kk = 0; kk < 4; kk++) {
            const int k0 = kk * 32 + quad * 8;
            const s16x8 a0 = *(const s16x8*)&obf[col][k0];
            const s16x8 a1 = *(const s16x8*)&obf[16 + col][k0];
#pragma unroll
            for (int nt = 0; nt < 2; nt++) {
                const int n = (wv4 * 2 + nt) * 16 + col;
                const s16x8 b = *(const s16x8*)&AF[n * DD + k0];
                facc[0][nt] = __builtin_amdgcn_mfma_f32_16x16x32_bf16(a0, b, facc[0][nt], 0, 0, 0);
                facc[1][nt] = __builtin_amdgcn_mfma_f32_16x16x32_bf16(a1, b, facc[1][nt], 0, 0, 0);
            }
        }

        // epilogue: u = facc + bias + residual(z); us overlays kf (dead)
#pragma unroll
        for (int mt = 0; mt < 2; mt++)
#pragma unroll
            for (int nt = 0; nt < 2; nt++) {
                const int n = (wv4 * 2 + nt) * 16 + col;
                const float bias = afb[n];
#pragma unroll
                for (int r = 0; r < 4; r++) {
                    const int i = mt * 16 + quad * 4 + r;
                    if (i >= 20) continue;
                    us[i][n] = facc[mt][nt][r] + bias + __bfloat162float(zs[i][n]);
                }
            }
    }
    __syncthreads();

    // --- LayerNorm per row, write bf16 in-place
    for (int i = wv4; i < KK; i += 4) {
        const float a0 = us[i][lane], a1 = us[i][lane + 64];
        const float s  = wave_sum(a0 + a1);
        const float sq = wave_sum(a0 * a0 + a1 * a1);
        const float mean = s * (1.0f / DD);
        const float var  = sq * (1.0f / DD) - mean * mean;
        const float inv  = rsqrtf(var + 1e-5f);
        zrow[i * DD + lane]      = __float2bfloat16((a0 - mean) * inv * lng[lane] + lnb[lane]);
        zrow[i * DD + lane + 64] = __float2bfloat16((a1 - mean) * inv * lng[lane + 64] + lnb[lane + 64]);
    }
}

// ---------------------------------------------------------------------------
// Kernel 3: FFN via bf16 MFMA. 32 rows/block, 4 waves.
// ---------------------------------------------------------------------------
#define XPAD (DD + 8)      // 136
#define HPAD (HIDD + 8)    // 520

__global__ __launch_bounds__(256)
void k3_ffn(bf16* __restrict__ zx,
            const bf16* __restrict__ w1t, const float* __restrict__ b1,
            const bf16* __restrict__ w2t, const float* __restrict__ b2,
            const float* __restrict__ lng, const float* __restrict__ lnb)
{
    __shared__ bf16 xs[32][XPAD];     // 8.5 KB
    __shared__ bf16 h1[32][HPAD];     // 32.5 KB ; reused as float u[32][128] after barrier

    const int t    = threadIdx.x;
    const int wv   = t >> 6;          // wave 0..3
    const int lane = t & 63;
    const int col  = lane & 15;
    const int quad = lane >> 4;       // 0..3
    const int base = blockIdx.x * 32 * DD;

    // --- stage x tile (32x128 bf16 = 8 KB), vectorized, pad-aware
    {
        const uint4* src = (const uint4*)(zx + base);   // 512 uint4
#pragma unroll
        for (int it = 0; it < 2; it++) {
            const int i = t + it * 256;                  // chunk of 8 bf16
            const int r = i >> 4, c = (i & 15) * 8;
            *(uint4*)&xs[r][c] = src[i];
        }
    }
    __syncthreads();

    // --- phase A: wave wv computes h1 cols [wv*128, wv*128+128)
    {
        f32x4 acc[2][8];
#pragma unroll
        for (int mt = 0; mt < 2; mt++)
#pragma unroll
            for (int nt = 0; nt < 8; nt++) acc[mt][nt] = (f32x4){0.f, 0.f, 0.f, 0.f};

#pragma unroll
        for (int kk = 0; kk < 4; kk++) {
            const int k0 = kk * 32 + quad * 8;
            const s16x8 a0 = *(const s16x8*)&xs[col][k0];
            const s16x8 a1 = *(const s16x8*)&xs[16 + col][k0];
#pragma unroll
            for (int nt = 0; nt < 8; nt++) {
                const int n = wv * 128 + nt * 16 + col;
                const s16x8 b = *(const s16x8*)&w1t[n * DD + k0];
                acc[0][nt] = __builtin_amdgcn_mfma_f32_16x16x32_bf16(a0, b, acc[0][nt], 0, 0, 0);
                acc[1][nt] = __builtin_amdgcn_mfma_f32_16x16x32_bf16(a1, b, acc[1][nt], 0, 0, 0);
            }
        }
#pragma unroll
        for (int nt = 0; nt < 8; nt++) {
            const int n = wv * 128 + nt * 16 + col;
            const float bias = b1[n];
#pragma unroll
            for (int r = 0; r < 4; r++) {
                const int row = quad * 4 + r;
                h1[row][n]      = __float2bfloat16(fmaxf(acc[0][nt][r] + bias, 0.f));
                h1[16 + row][n] = __float2bfloat16(fmaxf(acc[1][nt][r] + bias, 0.f));
            }
        }
    }
    __syncthreads();

    // --- phase B: wave wv computes u cols [wv*32, wv*32+32)
    {
        f32x4 acc[2][2];
#pragma unroll
        for (int mt = 0; mt < 2; mt++)
#pragma unroll
            for (int nt = 0; nt < 2; nt++) acc[mt][nt] = (f32x4){0.f, 0.f, 0.f, 0.f};

#pragma unroll 4
        for (int kk = 0; kk < 16; kk++) {
            const int k0 = kk * 32 + quad * 8;
            const s16x8 a0 = *(const s16x8*)&h1[col][k0];
            const s16x8 a1 = *(const s16x8*)&h1[16 + col][k0];
#pragma unroll
            for (int nt = 0; nt < 2; nt++) {
                const int n = wv * 32 + nt * 16 + col;
                const s16x8 b = *(const s16x8*)&w2t[n * HIDD + k0];
                acc[0][nt] = __builtin_amdgcn_mfma_f32_16x16x32_bf16(a0, b, acc[0][nt], 0, 0, 0);
                acc[1][nt] = __builtin_amdgcn_mfma_f32_16x16x32_bf16(a1, b, acc[1][nt], 0, 0, 0);
            }
        }
        __syncthreads();   // all waves done reading h1; safe to overwrite as u

        float* u = (float*)&h1[0][0];   // [32][128]
#pragma unroll
        for (int mt = 0; mt < 2; mt++)
#pragma unroll
            for (int nt = 0; nt < 2; nt++) {
                const int n = wv * 32 + nt * 16 + col;
                const float bias = b2[n];
#pragma unroll
                for (int r = 0; r < 4; r++) {
                    const int row = mt * 16 + quad * 4 + r;
                    u[row * DD + n] = acc[mt][nt][r] + bias + __bfloat162float(xs[row][n]);
                }
            }
    }
    __syncthreads();

    // --- LayerNorm per row, write bf16 in-place
    {
        const float* u = (const float*)&h1[0][0];
        for (int r = wv; r < 32; r += 4) {
            const float a0 = u[r * DD + lane], a1 = u[r * DD + lane + 64];
            const float s  = wave_sum(a0 + a1);
            const float sq = wave_sum(a0 * a0 + a1 * a1);
            const float mean = s * (1.0f / DD);
            const float var  = sq * (1.0f / DD) - mean * mean;
            const float inv  = rsqrtf(var + 1e-5f);
            zx[base + r * DD + lane]      = __float2bfloat16((a0 - mean) * inv * lng[lane] + lnb[lane]);
            zx[base + r * DD + lane + 64] = __float2bfloat16((a1 - mean) * inv * lng[lane + 64] + lnb[lane + 64]);
        }
    }
}

// ---------------------------------------------------------------------------
// Kernel 4: fuse self + neighborhood mean, fea2node, gelu, residual, LN -> out
// ---------------------------------------------------------------------------
__global__ __launch_bounds__(128)
void k4_fuse(const bf16* __restrict__ zx, const float* __restrict__ nhs,
             const float* __restrict__ fw, const float* __restrict__ fb,
             const float* __restrict__ lng, const float* __restrict__ lnb,
             float* __restrict__ out)
{
    __shared__ float f[2 * DD];
    __shared__ float red[4];
    const int d = threadIdx.x;
    const int node = blockIdx.x;
    const bf16* xr = zx + node * KK * DD;

    float nb = 0.f;
#pragma unroll
    for (int i = 0; i < KK - 1; i++) nb += __bfloat162float(xr[i * DD + d]);
    f[d] = __bfloat162float(xr[(KK - 1) * DD + d]);
    f[DD + d] = nb * (1.0f / (KK - 1));
    __syncthreads();

    float a = fb[d];
#pragma unroll 4
    for (int c = 0; c < 2 * DD; c++) a += f[c] * fw[c * DD + d];
    const float y = geluf(a) + nhs[(node * KK + KK - 1) * DD + d];

    float s = y, sq = y * y;
#pragma unroll
    for (int o = 32; o > 0; o >>= 1) {
        s += __shfl_down(s, o);
        sq += __shfl_down(sq, o);
    }
    const int wid = d >> 6, lane = d & 63;
    if (lane == 0) { red[wid] = s; red[2 + wid] = sq; }
    __syncthreads();
    const float ts = red[0] + red[1], tsq = red[2] + red[3];
    const float mean = ts * (1.0f / DD);
    const float var = tsq * (1.0f / DD) - mean * mean;
    const float inv = rsqrtf(var + 1e-5f);
    out[node * DD + d] = (y - mean) * inv * lng[d] + lnb[d];
}

// ---------------------------------------------------------------------------
extern "C" void kernel_launch(void* const* d_in, const int* in_sizes, int n_in,
                              void* d_out, int out_size, void* d_ws, size_t ws_size,
                              hipStream_t stream)
{
    const float* nhs   = (const float*)d_in[0];
    const float* t     = (const float*)d_in[1];
    const float* tnow  = (const float*)d_in[2];
    const float* ef    = (const float*)d_in[3];
    const float* freq  = (const float*)d_in[4];
    const float* phase = (const float*)d_in[5];
    const float* ew    = (const float*)d_in[6];
    const float* eb    = (const float*)d_in[7];
    const float* wq    = (const float*)d_in[8];
    const float* wk    = (const float*)d_in[9];
    const float* wv    = (const float*)d_in[10];
    const float* wqs   = (const float*)d_in[11];
    const float* afw   = (const float*)d_in[12];
    const float* afb   = (const float*)d_in[13];
    const float* alng  = (const float*)d_in[14];
    const float* alnb  = (const float*)d_in[15];
    const float* w1    = (const float*)d_in[16];
    const float* b1    = (const float*)d_in[17];
    const float* w2    = (const float*)d_in[18];
    const float* b2    = (const float*)d_in[19];
    const float* flng  = (const float*)d_in[20];
    const float* flnb  = (const float*)d_in[21];
    const float* fw    = (const float*)d_in[22];
    const float* fb    = (const float*)d_in[23];
    const float* olng  = (const float*)d_in[24];
    const float* olnb  = (const float*)d_in[25];
    float* out = (float*)d_out;

    bf16* zx  = (bf16*)d_ws;                                   // 102,400,000 B
    bf16* w1t = (bf16*)((char*)d_ws + (size_t)RTOT * DD * 2);  // +131072 B  [512][128]
    bf16* w2t = w1t + HIDD * DD;                               // +131072 B  [128][512]
    bf16* aw  = w2t + DD * HIDD;                               // +163840 B  5x[128][128]

    k0_conv<<<dim3(2 * HIDD * DD / 256), dim3(256), 0, stream>>>(w1, w2, w1t, w2t);
    k0b_conv<<<dim3(5 * DD * DD / 256), dim3(256), 0, stream>>>(wq, wk, wv, wqs, afw, aw);
    k1_msg<<<dim3(RTOT / 8), dim3(128, 8), 0, stream>>>(nhs, t, tnow, ef, freq, phase, ew, eb, zx);
    k2_attn<<<dim3(N_NODES), dim3(256), 0, stream>>>(zx, aw, afb, alng, alnb);
    k3_ffn<<<dim3(RTOT / 32), dim3(256), 0, stream>>>(zx, w1t, b1, w2t, b2, flng, flnb);
    k4_fuse<<<dim3(N_NODES), dim3(128), 0, stream>>>(zx, nhs, fw, fb, olng, olnb, out);
}

// Round 2
// 1404.771 us; speedup vs baseline: 2.2310x; 1.6410x over previous
//
#include <hip/hip_runtime.h>
#include <hip/hip_bf16.h>

// Problem constants
#define N_NODES 20000
#define KK 20
#define DD 128
#define HH 4
#define DKK 32
#define EE 128
#define HIDD 512
#define RTOT (N_NODES * KK)   // 400000 rows

using bf16 = __hip_bfloat16;

typedef short s16x8 __attribute__((ext_vector_type(8)));   // 8 bf16 in 4 VGPRs
typedef float f32x4 __attribute__((ext_vector_type(4)));

__device__ __forceinline__ float geluf(float x) {
    return 0.5f * x * (1.0f + erff(x * 0.70710678118654752f));
}

__device__ __forceinline__ float wave_sum(float v) {
#pragma unroll
    for (int o = 32; o > 0; o >>= 1) v += __shfl_down(v, o);
    return __shfl(v, 0);
}

// ---------------------------------------------------------------------------
// Kernel 0: convert FFN weights to transposed bf16 [N][K] layout.
// w1t[n][k] = w1[k][n]  (512 x 128);  w2t[n][k] = w2[k][n]  (128 x 512)
// ---------------------------------------------------------------------------
__global__ __launch_bounds__(256)
void k0_conv(const float* __restrict__ w1, const float* __restrict__ w2,
             bf16* __restrict__ w1t, bf16* __restrict__ w2t)
{
    const int id = blockIdx.x * 256 + threadIdx.x;   // 0 .. 131071
    if (id < HIDD * DD) {
        const int n = id / DD, k = id % DD;          // w1t[n][k]
        w1t[id] = __float2bfloat16(w1[k * HIDD + n]);
    } else {
        const int j = id - HIDD * DD;                // w2t: n<128, k<512
        const int n = j / HIDD, k = j % HIDD;
        w2t[j] = __float2bfloat16(w2[k * DD + n]);
    }
}

// ---------------------------------------------------------------------------
// Kernel 0b: convert attention + edge_fc weights to transposed bf16 [n][k].
// aw = [wqT | wkT | wvT | wqsT | afwT | ewT], each 128x128: T[n][k] = W[k][n]
// ---------------------------------------------------------------------------
__global__ __launch_bounds__(256)
void k0b_conv(const float* __restrict__ wq, const float* __restrict__ wk,
              const float* __restrict__ wv, const float* __restrict__ wqs,
              const float* __restrict__ afw, const float* __restrict__ ew,
              bf16* __restrict__ aw)
{
    const int id = blockIdx.x * 256 + threadIdx.x;   // 0 .. 98303
    const int m = id >> 14;                          // matrix 0..5
    const int r = id & 16383;
    const int n = r >> 7, k = r & 127;
    const float* src = (m == 0) ? wq : (m == 1) ? wk : (m == 2) ? wv
                     : (m == 3) ? wqs : (m == 4) ? afw : ew;
    aw[id] = __float2bfloat16(src[k * DD + n]);
}

// ---------------------------------------------------------------------------
// Kernel 1: z = node_h_src + gelu(edge_feat @ edge_fc_w + b) + cos((t_now-t)*freq+phase)
// MFMA edition: 32 rows/block, 4 waves; wave wv computes cols [wv*32, wv*32+32).
//   stage ef tile as bf16 -> MFMA vs ewt -> gelu to fp32 LDS -> coalesced
//   float4 epilogue (nhs + time-encoding) -> bf16 z.
// LDS: efs[32][136] bf16 (8704) + gs[32][132] f32 (16896) + ts[32] = 25.7 KB
// ---------------------------------------------------------------------------
__global__ __launch_bounds__(256)
void k1_msg(const float* __restrict__ nhs, const float* __restrict__ t,
            const float* __restrict__ t_now, const float* __restrict__ ef,
            const float* __restrict__ freq, const float* __restrict__ phase,
            const bf16* __restrict__ ewt, const float* __restrict__ eb,
            bf16* __restrict__ z)
{
    __shared__ bf16  efs[32][136];
    __shared__ float gs[32][132];
    __shared__ float ts[32];

    const int tid  = threadIdx.x;
    const int wv   = tid >> 6;          // wave 0..3
    const int lane = tid & 63;
    const int col  = lane & 15;
    const int quad = lane >> 4;         // 0..3
    const size_t base = (size_t)blockIdx.x * 32 * DD;

    // --- stage ef tile (32x128 fp32 -> bf16 LDS), coalesced float4
    {
        const float4* src = (const float4*)(ef + base);   // 1024 float4
#pragma unroll
        for (int it = 0; it < 4; it++) {
            const int i = tid + it * 256;
            const int r = i >> 5, c = (i & 31) * 4;
            const float4 v = src[i];
            bf16 tmp[4] = { __float2bfloat16(v.x), __float2bfloat16(v.y),
                            __float2bfloat16(v.z), __float2bfloat16(v.w) };
            *(uint2*)&efs[r][c] = *(const uint2*)tmp;
        }
    }
    if (tid < 32) ts[tid] = t[blockIdx.x * 32 + tid];
    __syncthreads();

    // --- edge_fc via MFMA: acc[mt][nt] covers rows mt*16+quad*4+[0,4), col n
    {
        f32x4 acc[2][2];
#pragma unroll
        for (int mt = 0; mt < 2; mt++)
#pragma unroll
            for (int nt = 0; nt < 2; nt++) acc[mt][nt] = (f32x4){0.f, 0.f, 0.f, 0.f};

#pragma unroll
        for (int kk = 0; kk < 4; kk++) {
            const int k0 = kk * 32 + quad * 8;
            const s16x8 a0 = *(const s16x8*)&efs[col][k0];
            const s16x8 a1 = *(const s16x8*)&efs[16 + col][k0];
#pragma unroll
            for (int nt = 0; nt < 2; nt++) {
                const int n = wv * 32 + nt * 16 + col;
                const s16x8 b = *(const s16x8*)&ewt[n * DD + k0];
                acc[0][nt] = __builtin_amdgcn_mfma_f32_16x16x32_bf16(a0, b, acc[0][nt], 0, 0, 0);
                acc[1][nt] = __builtin_amdgcn_mfma_f32_16x16x32_bf16(a1, b, acc[1][nt], 0, 0, 0);
            }
        }

        // gelu(acc + bias) -> gs
#pragma unroll
        for (int mt = 0; mt < 2; mt++)
#pragma unroll
            for (int nt = 0; nt < 2; nt++) {
                const int n = wv * 32 + nt * 16 + col;
                const float bias = eb[n];
#pragma unroll
                for (int r = 0; r < 4; r++) {
                    const int row = mt * 16 + quad * 4 + r;
                    gs[row][n] = geluf(acc[mt][nt][r] + bias);
                }
            }
    }
    __syncthreads();

    // --- epilogue: z = nhs + gs + cos((tn - t[row]) * freq + phase), coalesced
    {
        const float tn = t_now[0];
        const float4* nsrc = (const float4*)(nhs + base);
#pragma unroll
        for (int it = 0; it < 4; it++) {
            const int i = tid + it * 256;
            const int r = i >> 5, c = (i & 31) * 4;
            const float4 h  = nsrc[i];
            const float4 fq = *(const float4*)&freq[c];
            const float4 ph = *(const float4*)&phase[c];
            const float dt  = tn - ts[r];
            const float o0 = h.x + gs[r][c + 0] + __cosf(dt * fq.x + ph.x);
            const float o1 = h.y + gs[r][c + 1] + __cosf(dt * fq.y + ph.y);
            const float o2 = h.z + gs[r][c + 2] + __cosf(dt * fq.z + ph.z);
            const float o3 = h.w + gs[r][c + 3] + __cosf(dt * fq.w + ph.w);
            bf16 o[4] = { __float2bfloat16(o0), __float2bfloat16(o1),
                          __float2bfloat16(o2), __float2bfloat16(o3) };
            *(uint2*)&z[base + r * DD + c] = *(const uint2*)o;
        }
    }
}

// ---------------------------------------------------------------------------
// Kernel 2: per-node attention block, MFMA edition.
// ---------------------------------------------------------------------------
__global__ __launch_bounds__(256)
void k2_attn(bf16* __restrict__ zx, const bf16* __restrict__ aw,
             const float* __restrict__ afb,
             const float* __restrict__ lng, const float* __restrict__ lnb)
{
    __shared__ __align__(16) char smem[46784];
    bf16  (*zs)[136]     = (bf16  (*)[136])(smem);
    float (*qf)[132]     = (float (*)[132])(smem + 8704);
    float (*kf)[132]     = (float (*)[132])(smem + 19264);
    float (*vf)[132]     = (float (*)[132])(smem + 29824);
    float (*sc)[KK][KK]  = (float (*)[KK][KK])(smem + 40384);
    bf16  (*obf)[136]    = (bf16  (*)[136])(smem + 8704);    // overlays qf
    float (*us)[132]     = (float (*)[132])(smem + 19264);   // overlays kf

    const int t    = threadIdx.x;
    const int wv4  = t >> 6;          // wave 0..3
    const int lane = t & 63;
    const int col  = lane & 15;
    const int quad = lane >> 4;       // 0..3
    const int node = blockIdx.x;
    bf16* zrow = zx + node * KK * DD;

    const uint4 z4 = make_uint4(0u, 0u, 0u, 0u);

    // --- stage z tile (20x128 bf16) + zero pad rows 20..31
    {
        const uint4* src = (const uint4*)zrow;            // 320 chunks of 16B
        for (int i = t; i < 320; i += 256) {
            const int r = i >> 4, c = (i & 15) * 8;
            *(uint4*)&zs[r][c] = src[i];
        }
        for (int i = t; i < 204; i += 256) {              // 12 rows x 17 uint4
            const int r = 20 + i / 17, c = (i % 17) * 8;
            *(uint4*)&zs[r][c] = z4;
        }
    }
    __syncthreads();

    // --- QKV (+self_q) via MFMA: wave wv4 computes z @ W[wv4]
    {
        const bf16* Wm = aw + wv4 * (DD * DD);
        f32x4 acc[2][8];
#pragma unroll
        for (int mt = 0; mt < 2; mt++)
#pragma unroll
            for (int nt = 0; nt < 8; nt++) acc[mt][nt] = (f32x4){0.f, 0.f, 0.f, 0.f};

#pragma unroll
        for (int kk = 0; kk < 4; kk++) {
            const int k0 = kk * 32 + quad * 8;
            const s16x8 a0 = *(const s16x8*)&zs[col][k0];
            const s16x8 a1 = *(const s16x8*)&zs[16 + col][k0];
#pragma unroll
            for (int nt = 0; nt < 8; nt++) {
                const s16x8 b = *(const s16x8*)&Wm[(nt * 16 + col) * DD + k0];
                acc[0][nt] = __builtin_amdgcn_mfma_f32_16x16x32_bf16(a0, b, acc[0][nt], 0, 0, 0);
                acc[1][nt] = __builtin_amdgcn_mfma_f32_16x16x32_bf16(a1, b, acc[1][nt], 0, 0, 0);
            }
        }

        if (wv4 < 3) {
            float (*dst)[132] = (wv4 == 0) ? qf : (wv4 == 1) ? kf : vf;
#pragma unroll
            for (int mt = 0; mt < 2; mt++)
#pragma unroll
                for (int nt = 0; nt < 8; nt++)
#pragma unroll
                    for (int r = 0; r < 4; r++) {
                        const int row = mt * 16 + quad * 4 + r;
                        if (row >= 19) continue;          // 19 comes from self_q; >=20 pad
                        dst[row][nt * 16 + col] = acc[mt][nt][r];
                    }
        } else if (quad == 0) {                           // wave 3: self_q = z[19] @ wqs
#pragma unroll
            for (int nt = 0; nt < 8; nt++) {
                const int n = nt * 16 + col;
                const float s = acc[1][nt][3];            // D row 19 (mt=1,quad=0,r=3)
                qf[19][n] = s; kf[19][n] = s; vf[19][n] = s;
            }
        }
    }
    __syncthreads();

    // --- scores (fp32 VALU; 132-float row stride -> bank-stagger 4)
    const float scale = 0.17677669529663687f;
    for (int idx = t; idx < HH * KK * KK; idx += 256) {
        const int h = idx / (KK * KK);
        const int rem = idx % (KK * KK);
        const int i = rem / KK, j = rem % KK;
        float s = 0.f;
#pragma unroll
        for (int d = 0; d < DKK; d++)
            s += qf[i][h * DKK + d] * kf[j][h * DKK + d];
        sc[h][i][j] = s * scale;
    }
    __syncthreads();

    // --- softmax over j<20
    if (t < HH * KK) {
        const int h = t / KK, i = t % KK;
        float m = -1e30f;
#pragma unroll
        for (int j = 0; j < KK; j++) m = fmaxf(m, sc[h][i][j]);
        float s = 0.f;
#pragma unroll
        for (int j = 0; j < KK; j++) { const float e = __expf(sc[h][i][j] - m); sc[h][i][j] = e; s += e; }
        const float inv = 1.0f / s;
#pragma unroll
        for (int j = 0; j < KK; j++) sc[h][i][j] *= inv;
    }
    __syncthreads();

    // --- PV (fp32 VALU) -> O tile in bf16 (obf overlays qf; qf is dead)
    for (int idx = t; idx < KK * DD; idx += 256) {
        const int i = idx / DD, c = idx % DD, h = c / DKK;
        float o = 0.f;
#pragma unroll
        for (int j = 0; j < KK; j++) o += sc[h][i][j] * vf[j][c];
        obf[i][c] = __float2bfloat16(o);
    }
    for (int i = t; i < 204; i += 256) {                  // zero obf rows 20..31
        const int r = 20 + i / 17, c = (i % 17) * 8;
        *(uint4*)&obf[r][c] = z4;
    }
    __syncthreads();

    // --- attn_fc via MFMA: X = O @ afwT + afb + z, then rowwise LN
    {
        const bf16* AF = aw + 4 * (DD * DD);
        f32x4 facc[2][2];
#pragma unroll
        for (int mt = 0; mt < 2; mt++)
#pragma unroll
            for (int nt = 0; nt < 2; nt++) facc[mt][nt] = (f32x4){0.f, 0.f, 0.f, 0.f};

#pragma unroll
        for (int kk = 0; kk < 4; kk++) {
            const int k0 = kk * 32 + quad * 8;
            const s16x8 a0 = *(const s16x8*)&obf[col][k0];
            const s16x8 a1 = *(const s16x8*)&obf[16 + col][k0];
#pragma unroll
            for (int nt = 0; nt < 2; nt++) {
                const int n = (wv4 * 2 + nt) * 16 + col;
                const s16x8 b = *(const s16x8*)&AF[n * DD + k0];
                facc[0][nt] = __builtin_amdgcn_mfma_f32_16x16x32_bf16(a0, b, facc[0][nt], 0, 0, 0);
                facc[1][nt] = __builtin_amdgcn_mfma_f32_16x16x32_bf16(a1, b, facc[1][nt], 0, 0, 0);
            }
        }

        // epilogue: u = facc + bias + residual(z); us overlays kf (dead)
#pragma unroll
        for (int mt = 0; mt < 2; mt++)
#pragma unroll
            for (int nt = 0; nt < 2; nt++) {
                const int n = (wv4 * 2 + nt) * 16 + col;
                const float bias = afb[n];
#pragma unroll
                for (int r = 0; r < 4; r++) {
                    const int i = mt * 16 + quad * 4 + r;
                    if (i >= 20) continue;
                    us[i][n] = facc[mt][nt][r] + bias + __bfloat162float(zs[i][n]);
                }
            }
    }
    __syncthreads();

    // --- LayerNorm per row, write bf16 in-place
    for (int i = wv4; i < KK; i += 4) {
        const float a0 = us[i][lane], a1 = us[i][lane + 64];
        const float s  = wave_sum(a0 + a1);
        const float sq = wave_sum(a0 * a0 + a1 * a1);
        const float mean = s * (1.0f / DD);
        const float var  = sq * (1.0f / DD) - mean * mean;
        const float inv  = rsqrtf(var + 1e-5f);
        zrow[i * DD + lane]      = __float2bfloat16((a0 - mean) * inv * lng[lane] + lnb[lane]);
        zrow[i * DD + lane + 64] = __float2bfloat16((a1 - mean) * inv * lng[lane + 64] + lnb[lane + 64]);
    }
}

// ---------------------------------------------------------------------------
// Kernel 3: FFN via bf16 MFMA. 32 rows/block, 4 waves.
// ---------------------------------------------------------------------------
#define XPAD (DD + 8)      // 136
#define HPAD (HIDD + 8)    // 520

__global__ __launch_bounds__(256)
void k3_ffn(bf16* __restrict__ zx,
            const bf16* __restrict__ w1t, const float* __restrict__ b1,
            const bf16* __restrict__ w2t, const float* __restrict__ b2,
            const float* __restrict__ lng, const float* __restrict__ lnb)
{
    __shared__ bf16 xs[32][XPAD];     // 8.5 KB
    __shared__ bf16 h1[32][HPAD];     // 32.5 KB ; reused as float u[32][128] after barrier

    const int t    = threadIdx.x;
    const int wv   = t >> 6;          // wave 0..3
    const int lane = t & 63;
    const int col  = lane & 15;
    const int quad = lane >> 4;       // 0..3
    const int base = blockIdx.x * 32 * DD;

    // --- stage x tile (32x128 bf16 = 8 KB), vectorized, pad-aware
    {
        const uint4* src = (const uint4*)(zx + base);   // 512 uint4
#pragma unroll
        for (int it = 0; it < 2; it++) {
            const int i = t + it * 256;                  // chunk of 8 bf16
            const int r = i >> 4, c = (i & 15) * 8;
            *(uint4*)&xs[r][c] = src[i];
        }
    }
    __syncthreads();

    // --- phase A: wave wv computes h1 cols [wv*128, wv*128+128)
    {
        f32x4 acc[2][8];
#pragma unroll
        for (int mt = 0; mt < 2; mt++)
#pragma unroll
            for (int nt = 0; nt < 8; nt++) acc[mt][nt] = (f32x4){0.f, 0.f, 0.f, 0.f};

#pragma unroll
        for (int kk = 0; kk < 4; kk++) {
            const int k0 = kk * 32 + quad * 8;
            const s16x8 a0 = *(const s16x8*)&xs[col][k0];
            const s16x8 a1 = *(const s16x8*)&xs[16 + col][k0];
#pragma unroll
            for (int nt = 0; nt < 8; nt++) {
                const int n = wv * 128 + nt * 16 + col;
                const s16x8 b = *(const s16x8*)&w1t[n * DD + k0];
                acc[0][nt] = __builtin_amdgcn_mfma_f32_16x16x32_bf16(a0, b, acc[0][nt], 0, 0, 0);
                acc[1][nt] = __builtin_amdgcn_mfma_f32_16x16x32_bf16(a1, b, acc[1][nt], 0, 0, 0);
            }
        }
#pragma unroll
        for (int nt = 0; nt < 8; nt++) {
            const int n = wv * 128 + nt * 16 + col;
            const float bias = b1[n];
#pragma unroll
            for (int r = 0; r < 4; r++) {
                const int row = quad * 4 + r;
                h1[row][n]      = __float2bfloat16(fmaxf(acc[0][nt][r] + bias, 0.f));
                h1[16 + row][n] = __float2bfloat16(fmaxf(acc[1][nt][r] + bias, 0.f));
            }
        }
    }
    __syncthreads();

    // --- phase B: wave wv computes u cols [wv*32, wv*32+32)
    {
        f32x4 acc[2][2];
#pragma unroll
        for (int mt = 0; mt < 2; mt++)
#pragma unroll
            for (int nt = 0; nt < 2; nt++) acc[mt][nt] = (f32x4){0.f, 0.f, 0.f, 0.f};

#pragma unroll 4
        for (int kk = 0; kk < 16; kk++) {
            const int k0 = kk * 32 + quad * 8;
            const s16x8 a0 = *(const s16x8*)&h1[col][k0];
            const s16x8 a1 = *(const s16x8*)&h1[16 + col][k0];
#pragma unroll
            for (int nt = 0; nt < 2; nt++) {
                const int n = wv * 32 + nt * 16 + col;
                const s16x8 b = *(const s16x8*)&w2t[n * HIDD + k0];
                acc[0][nt] = __builtin_amdgcn_mfma_f32_16x16x32_bf16(a0, b, acc[0][nt], 0, 0, 0);
                acc[1][nt] = __builtin_amdgcn_mfma_f32_16x16x32_bf16(a1, b, acc[1][nt], 0, 0, 0);
            }
        }
        __syncthreads();   // all waves done reading h1; safe to overwrite as u

        float* u = (float*)&h1[0][0];   // [32][128]
#pragma unroll
        for (int mt = 0; mt < 2; mt++)
#pragma unroll
            for (int nt = 0; nt < 2; nt++) {
                const int n = wv * 32 + nt * 16 + col;
                const float bias = b2[n];
#pragma unroll
                for (int r = 0; r < 4; r++) {
                    const int row = mt * 16 + quad * 4 + r;
                    u[row * DD + n] = acc[mt][nt][r] + bias + __bfloat162float(xs[row][n]);
                }
            }
    }
    __syncthreads();

    // --- LayerNorm per row, write bf16 in-place
    {
        const float* u = (const float*)&h1[0][0];
        for (int r = wv; r < 32; r += 4) {
            const float a0 = u[r * DD + lane], a1 = u[r * DD + lane + 64];
            const float s  = wave_sum(a0 + a1);
            const float sq = wave_sum(a0 * a0 + a1 * a1);
            const float mean = s * (1.0f / DD);
            const float var  = sq * (1.0f / DD) - mean * mean;
            const float inv  = rsqrtf(var + 1e-5f);
            zx[base + r * DD + lane]      = __float2bfloat16((a0 - mean) * inv * lng[lane] + lnb[lane]);
            zx[base + r * DD + lane + 64] = __float2bfloat16((a1 - mean) * inv * lng[lane + 64] + lnb[lane + 64]);
        }
    }
}

// ---------------------------------------------------------------------------
// Kernel 4: fuse self + neighborhood mean, fea2node, gelu, residual, LN -> out
// ---------------------------------------------------------------------------
__global__ __launch_bounds__(128)
void k4_fuse(const bf16* __restrict__ zx, const float* __restrict__ nhs,
             const float* __restrict__ fw, const float* __restrict__ fb,
             const float* __restrict__ lng, const float* __restrict__ lnb,
             float* __restrict__ out)
{
    __shared__ float f[2 * DD];
    __shared__ float red[4];
    const int d = threadIdx.x;
    const int node = blockIdx.x;
    const bf16* xr = zx + node * KK * DD;

    float nb = 0.f;
#pragma unroll
    for (int i = 0; i < KK - 1; i++) nb += __bfloat162float(xr[i * DD + d]);
    f[d] = __bfloat162float(xr[(KK - 1) * DD + d]);
    f[DD + d] = nb * (1.0f / (KK - 1));
    __syncthreads();

    float a = fb[d];
#pragma unroll 4
    for (int c = 0; c < 2 * DD; c++) a += f[c] * fw[c * DD + d];
    const float y = geluf(a) + nhs[(node * KK + KK - 1) * DD + d];

    float s = y, sq = y * y;
#pragma unroll
    for (int o = 32; o > 0; o >>= 1) {
        s += __shfl_down(s, o);
        sq += __shfl_down(sq, o);
    }
    const int wid = d >> 6, lane = d & 63;
    if (lane == 0) { red[wid] = s; red[2 + wid] = sq; }
    __syncthreads();
    const float ts = red[0] + red[1], tsq = red[2] + red[3];
    const float mean = ts * (1.0f / DD);
    const float var = tsq * (1.0f / DD) - mean * mean;
    const float inv = rsqrtf(var + 1e-5f);
    out[node * DD + d] = (y - mean) * inv * lng[d] + lnb[d];
}

// ---------------------------------------------------------------------------
extern "C" void kernel_launch(void* const* d_in, const int* in_sizes, int n_in,
                              void* d_out, int out_size, void* d_ws, size_t ws_size,
                              hipStream_t stream)
{
    const float* nhs   = (const float*)d_in[0];
    const float* t     = (const float*)d_in[1];
    const float* tnow  = (const float*)d_in[2];
    const float* ef    = (const float*)d_in[3];
    const float* freq  = (const float*)d_in[4];
    const float* phase = (const float*)d_in[5];
    const float* ew    = (const float*)d_in[6];
    const float* eb    = (const float*)d_in[7];
    const float* wq    = (const float*)d_in[8];
    const float* wk    = (const float*)d_in[9];
    const float* wv    = (const float*)d_in[10];
    const float* wqs   = (const float*)d_in[11];
    const float* afw   = (const float*)d_in[12];
    const float* afb   = (const float*)d_in[13];
    const float* alng  = (const float*)d_in[14];
    const float* alnb  = (const float*)d_in[15];
    const float* w1    = (const float*)d_in[16];
    const float* b1    = (const float*)d_in[17];
    const float* w2    = (const float*)d_in[18];
    const float* b2    = (const float*)d_in[19];
    const float* flng  = (const float*)d_in[20];
    const float* flnb  = (const float*)d_in[21];
    const float* fw    = (const float*)d_in[22];
    const float* fb    = (const float*)d_in[23];
    const float* olng  = (const float*)d_in[24];
    const float* olnb  = (const float*)d_in[25];
    float* out = (float*)d_out;

    bf16* zx  = (bf16*)d_ws;                                   // 102,400,000 B
    bf16* w1t = (bf16*)((char*)d_ws + (size_t)RTOT * DD * 2);  // +131072 B  [512][128]
    bf16* w2t = w1t + HIDD * DD;                               // +131072 B  [128][512]
    bf16* aw  = w2t + DD * HIDD;                               // +196608 B  6x[128][128]
    bf16* ewt = aw + 5 * DD * DD;                              // last matrix of aw

    k0_conv<<<dim3(2 * HIDD * DD / 256), dim3(256), 0, stream>>>(w1, w2, w1t, w2t);
    k0b_conv<<<dim3(6 * DD * DD / 256), dim3(256), 0, stream>>>(wq, wk, wv, wqs, afw, ew, aw);
    k1_msg<<<dim3(RTOT / 32), dim3(256), 0, stream>>>(nhs, t, tnow, ef, freq, phase, ewt, eb, zx);
    k2_attn<<<dim3(N_NODES), dim3(256), 0, stream>>>(zx, aw, afb, alng, alnb);
    k3_ffn<<<dim3(RTOT / 32), dim3(256), 0, stream>>>(zx, w1t, b1, w2t, b2, flng, flnb);
    k4_fuse<<<dim3(N_NODES), dim3(128), 0, stream>>>(zx, nhs, fw, fb, olng, olnb, out);
}

// Round 3
// 1367.241 us; speedup vs baseline: 2.2923x; 1.0274x over previous
//
#include <hip/hip_runtime.h>
#include <hip/hip_bf16.h>

// Problem constants
#define N_NODES 20000
#define KK 20
#define DD 128
#define HH 4
#define DKK 32
#define EE 128
#define HIDD 512
#define RTOT (N_NODES * KK)   // 400000 rows

using bf16 = __hip_bfloat16;

typedef short s16x8 __attribute__((ext_vector_type(8)));   // 8 bf16 in 4 VGPRs
typedef float f32x4 __attribute__((ext_vector_type(4)));

__device__ __forceinline__ float geluf(float x) {
    return 0.5f * x * (1.0f + erff(x * 0.70710678118654752f));
}

__device__ __forceinline__ float wave_sum(float v) {
#pragma unroll
    for (int o = 32; o > 0; o >>= 1) v += __shfl_down(v, o);
    return __shfl(v, 0);
}

// ---------------------------------------------------------------------------
// Kernel 0: convert FFN weights to transposed bf16 [N][K] layout.
// w1t[n][k] = w1[k][n]  (512 x 128);  w2t[n][k] = w2[k][n]  (128 x 512)
// ---------------------------------------------------------------------------
__global__ __launch_bounds__(256)
void k0_conv(const float* __restrict__ w1, const float* __restrict__ w2,
             bf16* __restrict__ w1t, bf16* __restrict__ w2t)
{
    const int id = blockIdx.x * 256 + threadIdx.x;   // 0 .. 131071
    if (id < HIDD * DD) {
        const int n = id / DD, k = id % DD;          // w1t[n][k]
        w1t[id] = __float2bfloat16(w1[k * HIDD + n]);
    } else {
        const int j = id - HIDD * DD;                // w2t: n<128, k<512
        const int n = j / HIDD, k = j % HIDD;
        w2t[j] = __float2bfloat16(w2[k * DD + n]);
    }
}

// ---------------------------------------------------------------------------
// Kernel 0b: convert attention + edge_fc weights to transposed bf16 [n][k].
// aw = [wqT | wkT | wvT | wqsT | afwT | ewT], each 128x128: T[n][k] = W[k][n]
// ---------------------------------------------------------------------------
__global__ __launch_bounds__(256)
void k0b_conv(const float* __restrict__ wq, const float* __restrict__ wk,
              const float* __restrict__ wv, const float* __restrict__ wqs,
              const float* __restrict__ afw, const float* __restrict__ ew,
              bf16* __restrict__ aw)
{
    const int id = blockIdx.x * 256 + threadIdx.x;   // 0 .. 98303
    const int m = id >> 14;                          // matrix 0..5
    const int r = id & 16383;
    const int n = r >> 7, k = r & 127;
    const float* src = (m == 0) ? wq : (m == 1) ? wk : (m == 2) ? wv
                     : (m == 3) ? wqs : (m == 4) ? afw : ew;
    aw[id] = __float2bfloat16(src[k * DD + n]);
}

// ---------------------------------------------------------------------------
// Kernel 1: z = node_h_src + gelu(edge_feat @ edge_fc_w + b) + cos((t_now-t)*freq+phase)
// MFMA edition: 32 rows/block, 4 waves; wave wv computes cols [wv*32, wv*32+32).
// ---------------------------------------------------------------------------
__global__ __launch_bounds__(256)
void k1_msg(const float* __restrict__ nhs, const float* __restrict__ t,
            const float* __restrict__ t_now, const float* __restrict__ ef,
            const float* __restrict__ freq, const float* __restrict__ phase,
            const bf16* __restrict__ ewt, const float* __restrict__ eb,
            bf16* __restrict__ z)
{
    __shared__ bf16  efs[32][136];
    __shared__ float gs[32][132];
    __shared__ float ts[32];

    const int tid  = threadIdx.x;
    const int wv   = tid >> 6;          // wave 0..3
    const int lane = tid & 63;
    const int col  = lane & 15;
    const int quad = lane >> 4;         // 0..3
    const size_t base = (size_t)blockIdx.x * 32 * DD;

    // --- stage ef tile (32x128 fp32 -> bf16 LDS), coalesced float4
    {
        const float4* src = (const float4*)(ef + base);   // 1024 float4
#pragma unroll
        for (int it = 0; it < 4; it++) {
            const int i = tid + it * 256;
            const int r = i >> 5, c = (i & 31) * 4;
            const float4 v = src[i];
            bf16 tmp[4] = { __float2bfloat16(v.x), __float2bfloat16(v.y),
                            __float2bfloat16(v.z), __float2bfloat16(v.w) };
            *(uint2*)&efs[r][c] = *(const uint2*)tmp;
        }
    }
    if (tid < 32) ts[tid] = t[blockIdx.x * 32 + tid];
    __syncthreads();

    // --- edge_fc via MFMA
    {
        f32x4 acc[2][2];
#pragma unroll
        for (int mt = 0; mt < 2; mt++)
#pragma unroll
            for (int nt = 0; nt < 2; nt++) acc[mt][nt] = (f32x4){0.f, 0.f, 0.f, 0.f};

#pragma unroll
        for (int kk = 0; kk < 4; kk++) {
            const int k0 = kk * 32 + quad * 8;
            const s16x8 a0 = *(const s16x8*)&efs[col][k0];
            const s16x8 a1 = *(const s16x8*)&efs[16 + col][k0];
#pragma unroll
            for (int nt = 0; nt < 2; nt++) {
                const int n = wv * 32 + nt * 16 + col;
                const s16x8 b = *(const s16x8*)&ewt[n * DD + k0];
                acc[0][nt] = __builtin_amdgcn_mfma_f32_16x16x32_bf16(a0, b, acc[0][nt], 0, 0, 0);
                acc[1][nt] = __builtin_amdgcn_mfma_f32_16x16x32_bf16(a1, b, acc[1][nt], 0, 0, 0);
            }
        }

        // gelu(acc + bias) -> gs
#pragma unroll
        for (int mt = 0; mt < 2; mt++)
#pragma unroll
            for (int nt = 0; nt < 2; nt++) {
                const int n = wv * 32 + nt * 16 + col;
                const float bias = eb[n];
#pragma unroll
                for (int r = 0; r < 4; r++) {
                    const int row = mt * 16 + quad * 4 + r;
                    gs[row][n] = geluf(acc[mt][nt][r] + bias);
                }
            }
    }
    __syncthreads();

    // --- epilogue: z = nhs + gs + cos((tn - t[row]) * freq + phase), coalesced
    {
        const float tn = t_now[0];
        const float4* nsrc = (const float4*)(nhs + base);
#pragma unroll
        for (int it = 0; it < 4; it++) {
            const int i = tid + it * 256;
            const int r = i >> 5, c = (i & 31) * 4;
            const float4 h  = nsrc[i];
            const float4 fq = *(const float4*)&freq[c];
            const float4 ph = *(const float4*)&phase[c];
            const float dt  = tn - ts[r];
            const float o0 = h.x + gs[r][c + 0] + __cosf(dt * fq.x + ph.x);
            const float o1 = h.y + gs[r][c + 1] + __cosf(dt * fq.y + ph.y);
            const float o2 = h.z + gs[r][c + 2] + __cosf(dt * fq.z + ph.z);
            const float o3 = h.w + gs[r][c + 3] + __cosf(dt * fq.w + ph.w);
            bf16 o[4] = { __float2bfloat16(o0), __float2bfloat16(o1),
                          __float2bfloat16(o2), __float2bfloat16(o3) };
            *(uint2*)&z[base + r * DD + c] = *(const uint2*)o;
        }
    }
}

// ---------------------------------------------------------------------------
// Kernel 2: per-node attention block, full-MFMA edition.
//   QKV:  bf16 MFMA -> qb/kb bf16 tiles, V transposed -> vT[n][j] bf16.
//   scores: per head-wave 4x MFMA (K=32); softmax fully in registers via
//           16-lane shfl_xor reduce (all 256 threads active).
//   PV:   P -> bf16 LDS [4][32][40] (j>=20 zero), 4x MFMA per head-wave.
//   attn_fc: bf16 MFMA from obf; fused residual + rowwise LN.
// LDS (byte offsets):
//   zs  [32][136] bf16 @ 0      (8704)   live whole kernel (residual)
//   qb  [32][136] bf16 @ 8704   (8704)   dead after scores
//   kb  [32][136] bf16 @ 17408  (8704)   dead after scores
//   vT  [128][40] bf16 @ 26112  (10240)  dead after PV
//   Pm  [4][32][40] bf16 @ 8704 (10240)  overlays qb/kb
//   obf [32][136] bf16 @ 8704   (8704)   overlays Pm
//   us  [20][132] f32  @ 8704   (10560)  overlays obf
// total 36352 B -> 4 blocks/CU (was 3)
// ---------------------------------------------------------------------------
__global__ __launch_bounds__(256, 4)
void k2_attn(bf16* __restrict__ zx, const bf16* __restrict__ aw,
             const float* __restrict__ afb,
             const float* __restrict__ lng, const float* __restrict__ lnb)
{
    __shared__ __align__(16) char smem[36352];
    bf16  (*zs)[136]    = (bf16  (*)[136])(smem);
    bf16  (*qb)[136]    = (bf16  (*)[136])(smem + 8704);
    bf16  (*kb)[136]    = (bf16  (*)[136])(smem + 17408);
    bf16  (*vT)[40]     = (bf16  (*)[40]) (smem + 26112);
    bf16  (*Pm)[32][40] = (bf16  (*)[32][40])(smem + 8704);   // overlays qb/kb
    bf16  (*obf)[136]   = (bf16  (*)[136])(smem + 8704);      // overlays Pm
    float (*us)[132]    = (float (*)[132])(smem + 8704);      // overlays obf

    const int t    = threadIdx.x;
    const int wv4  = t >> 6;          // wave 0..3 == head id in attn phases
    const int lane = t & 63;
    const int col  = lane & 15;
    const int quad = lane >> 4;       // 0..3
    const int node = blockIdx.x;
    bf16* zrow = zx + node * KK * DD;

    const uint4 z4 = make_uint4(0u, 0u, 0u, 0u);

    // --- stage z tile (20x128 bf16) + zero pad rows 20..31
    {
        const uint4* src = (const uint4*)zrow;            // 320 chunks of 16B
        for (int i = t; i < 320; i += 256) {
            const int r = i >> 4, c = (i & 15) * 8;
            *(uint4*)&zs[r][c] = src[i];
        }
        for (int i = t; i < 204; i += 256) {              // 12 rows x 17 uint4
            const int r = 20 + i / 17, c = (i % 17) * 8;
            *(uint4*)&zs[r][c] = z4;
        }
    }
    __syncthreads();

    // --- QKV (+self_q) via MFMA: wave wv4 computes z @ W[wv4]
    {
        const bf16* Wm = aw + wv4 * (DD * DD);
        f32x4 acc[2][8];
#pragma unroll
        for (int mt = 0; mt < 2; mt++)
#pragma unroll
            for (int nt = 0; nt < 8; nt++) acc[mt][nt] = (f32x4){0.f, 0.f, 0.f, 0.f};

#pragma unroll
        for (int kk = 0; kk < 4; kk++) {
            const int k0 = kk * 32 + quad * 8;
            const s16x8 a0 = *(const s16x8*)&zs[col][k0];
            const s16x8 a1 = *(const s16x8*)&zs[16 + col][k0];
#pragma unroll
            for (int nt = 0; nt < 8; nt++) {
                const s16x8 b = *(const s16x8*)&Wm[(nt * 16 + col) * DD + k0];
                acc[0][nt] = __builtin_amdgcn_mfma_f32_16x16x32_bf16(a0, b, acc[0][nt], 0, 0, 0);
                acc[1][nt] = __builtin_amdgcn_mfma_f32_16x16x32_bf16(a1, b, acc[1][nt], 0, 0, 0);
            }
        }

        if (wv4 < 2) {
            bf16 (*dst)[136] = (wv4 == 0) ? qb : kb;      // rows 0..18
#pragma unroll
            for (int mt = 0; mt < 2; mt++)
#pragma unroll
                for (int nt = 0; nt < 8; nt++)
#pragma unroll
                    for (int r = 0; r < 4; r++) {
                        const int row = mt * 16 + quad * 4 + r;
                        if (row >= 19) continue;          // 19 from self_q; >=20 unused
                        dst[row][nt * 16 + col] = __float2bfloat16(acc[mt][nt][r]);
                    }
        } else if (wv4 == 2) {                            // V -> transposed vT[n][j]
#pragma unroll
            for (int mt = 0; mt < 2; mt++)
#pragma unroll
                for (int nt = 0; nt < 8; nt++)
#pragma unroll
                    for (int r = 0; r < 4; r++) {
                        const int row = mt * 16 + quad * 4 + r;
                        if (row == 19) continue;          // self_q slot
                        // rows 20..31 are genuine zeros (z pad rows) - must write
                        vT[nt * 16 + col][row] = __float2bfloat16(acc[mt][nt][r]);
                    }
        } else if (quad == 0) {                           // wave 3: self_q = z[19] @ wqs
#pragma unroll
            for (int nt = 0; nt < 8; nt++) {
                const int n = nt * 16 + col;
                const bf16 s = __float2bfloat16(acc[1][nt][3]);  // D row 19
                qb[19][n] = s; kb[19][n] = s; vT[n][19] = s;
            }
        }
    }
    __syncthreads();

    // --- scores via MFMA + in-register softmax (head h = wv4)
    float p0[2][4], p1[2][4];
    {
        const int hb = wv4 * DKK;
        const int k0 = quad * 8;
        const s16x8 qa0 = *(const s16x8*)&qb[col][hb + k0];
        const s16x8 qa1 = *(const s16x8*)&qb[16 + col][hb + k0];
        const s16x8 kf0 = *(const s16x8*)&kb[col][hb + k0];
        const s16x8 kf1 = *(const s16x8*)&kb[16 + col][hb + k0];
        const f32x4 zero = (f32x4){0.f, 0.f, 0.f, 0.f};
        f32x4 sacc[2][2];
        sacc[0][0] = __builtin_amdgcn_mfma_f32_16x16x32_bf16(qa0, kf0, zero, 0, 0, 0);
        sacc[0][1] = __builtin_amdgcn_mfma_f32_16x16x32_bf16(qa0, kf1, zero, 0, 0, 0);
        sacc[1][0] = __builtin_amdgcn_mfma_f32_16x16x32_bf16(qa1, kf0, zero, 0, 0, 0);
        sacc[1][1] = __builtin_amdgcn_mfma_f32_16x16x32_bf16(qa1, kf1, zero, 0, 0, 0);

        const float scale = 0.17677669529663687f;
#pragma unroll
        for (int mt = 0; mt < 2; mt++)
#pragma unroll
            for (int r = 0; r < 4; r++) {
                // lane (quad,col) holds S[i][j]: i = mt*16+quad*4+r, j = {col, 16+col}
                const float s0 = sacc[mt][0][r] * scale;
                const float s1 = sacc[mt][1][r] * scale;
                float mx = fmaxf(s0, (col < 4) ? s1 : -1e30f);
#pragma unroll
                for (int o = 1; o < 16; o <<= 1) mx = fmaxf(mx, __shfl_xor(mx, o));
                const float e0 = __expf(s0 - mx);
                const float e1 = (col < 4) ? __expf(s1 - mx) : 0.f;
                float sm = e0 + e1;
#pragma unroll
                for (int o = 1; o < 16; o <<= 1) sm += __shfl_xor(sm, o);
                const float inv = 1.0f / sm;
                p0[mt][r] = e0 * inv;
                p1[mt][r] = e1 * inv;                     // 0 for j>=20
            }
    }
    __syncthreads();   // all qb/kb reads done; safe to overwrite with Pm

    // --- write P (bf16, j=16..31 includes zeros for j>=20)
#pragma unroll
    for (int mt = 0; mt < 2; mt++)
#pragma unroll
        for (int r = 0; r < 4; r++) {
            const int i = mt * 16 + quad * 4 + r;
            Pm[wv4][i][col]      = __float2bfloat16(p0[mt][r]);
            Pm[wv4][i][16 + col] = __float2bfloat16(p1[mt][r]);
        }
    // intra-wave write->read on Pm[wv4]: compiler orders via lgkmcnt; no barrier

    // --- PV via MFMA: O_h = P_h @ V_h
    f32x4 oacc[2][2];
    {
        const int hb = wv4 * DKK;
        const int k0 = quad * 8;
        const s16x8 pa0 = *(const s16x8*)&Pm[wv4][col][k0];
        const s16x8 pa1 = *(const s16x8*)&Pm[wv4][16 + col][k0];
        const s16x8 vb0 = *(const s16x8*)&vT[hb + col][k0];
        const s16x8 vb1 = *(const s16x8*)&vT[hb + 16 + col][k0];
        const f32x4 zero = (f32x4){0.f, 0.f, 0.f, 0.f};
        oacc[0][0] = __builtin_amdgcn_mfma_f32_16x16x32_bf16(pa0, vb0, zero, 0, 0, 0);
        oacc[0][1] = __builtin_amdgcn_mfma_f32_16x16x32_bf16(pa0, vb1, zero, 0, 0, 0);
        oacc[1][0] = __builtin_amdgcn_mfma_f32_16x16x32_bf16(pa1, vb0, zero, 0, 0, 0);
        oacc[1][1] = __builtin_amdgcn_mfma_f32_16x16x32_bf16(pa1, vb1, zero, 0, 0, 0);
    }
    __syncthreads();   // all Pm/vT reads done; safe to overwrite with obf

    // --- write O tile (bf16); rows 20..31 garbage but only feed discarded m-rows
    {
        const int hb = wv4 * DKK;
#pragma unroll
        for (int mt = 0; mt < 2; mt++)
#pragma unroll
            for (int nt = 0; nt < 2; nt++)
#pragma unroll
                for (int r = 0; r < 4; r++)
                    obf[mt * 16 + quad * 4 + r][hb + nt * 16 + col] =
                        __float2bfloat16(oacc[mt][nt][r]);
    }
    __syncthreads();

    // --- attn_fc via MFMA: X = O @ afwT + afb + z, then rowwise LN
    {
        const bf16* AF = aw + 4 * (DD * DD);
        f32x4 facc[2][2];
#pragma unroll
        for (int mt = 0; mt < 2; mt++)
#pragma unroll
            for (int nt = 0; nt < 2; nt++) facc[mt][nt] = (f32x4){0.f, 0.f, 0.f, 0.f};

#pragma unroll
        for (int kk = 0; kk < 4; kk++) {
            const int k0 = kk * 32 + quad * 8;
            const s16x8 a0 = *(const s16x8*)&obf[col][k0];
            const s16x8 a1 = *(const s16x8*)&obf[16 + col][k0];
#pragma unroll
            for (int nt = 0; nt < 2; nt++) {
                const int n = (wv4 * 2 + nt) * 16 + col;
                const s16x8 b = *(const s16x8*)&AF[n * DD + k0];
                facc[0][nt] = __builtin_amdgcn_mfma_f32_16x16x32_bf16(a0, b, facc[0][nt], 0, 0, 0);
                facc[1][nt] = __builtin_amdgcn_mfma_f32_16x16x32_bf16(a1, b, facc[1][nt], 0, 0, 0);
            }
        }
        __syncthreads();   // all obf reads done; safe to overwrite with us

        // epilogue: u = facc + bias + residual(z)
#pragma unroll
        for (int mt = 0; mt < 2; mt++)
#pragma unroll
            for (int nt = 0; nt < 2; nt++) {
                const int n = (wv4 * 2 + nt) * 16 + col;
                const float bias = afb[n];
#pragma unroll
                for (int r = 0; r < 4; r++) {
                    const int i = mt * 16 + quad * 4 + r;
                    if (i >= 20) continue;
                    us[i][n] = facc[mt][nt][r] + bias + __bfloat162float(zs[i][n]);
                }
            }
    }
    __syncthreads();

    // --- LayerNorm per row, write bf16 in-place
    for (int i = wv4; i < KK; i += 4) {
        const float a0 = us[i][lane], a1 = us[i][lane + 64];
        const float s  = wave_sum(a0 + a1);
        const float sq = wave_sum(a0 * a0 + a1 * a1);
        const float mean = s * (1.0f / DD);
        const float var  = sq * (1.0f / DD) - mean * mean;
        const float inv  = rsqrtf(var + 1e-5f);
        zrow[i * DD + lane]      = __float2bfloat16((a0 - mean) * inv * lng[lane] + lnb[lane]);
        zrow[i * DD + lane + 64] = __float2bfloat16((a1 - mean) * inv * lng[lane + 64] + lnb[lane + 64]);
    }
}

// ---------------------------------------------------------------------------
// Kernel 3: FFN via bf16 MFMA. 32 rows/block, 4 waves.
// ---------------------------------------------------------------------------
#define XPAD (DD + 8)      // 136
#define HPAD (HIDD + 8)    // 520

__global__ __launch_bounds__(256)
void k3_ffn(bf16* __restrict__ zx,
            const bf16* __restrict__ w1t, const float* __restrict__ b1,
            const bf16* __restrict__ w2t, const float* __restrict__ b2,
            const float* __restrict__ lng, const float* __restrict__ lnb)
{
    __shared__ bf16 xs[32][XPAD];     // 8.5 KB
    __shared__ bf16 h1[32][HPAD];     // 32.5 KB ; reused as float u[32][128] after barrier

    const int t    = threadIdx.x;
    const int wv   = t >> 6;          // wave 0..3
    const int lane = t & 63;
    const int col  = lane & 15;
    const int quad = lane >> 4;       // 0..3
    const int base = blockIdx.x * 32 * DD;

    // --- stage x tile (32x128 bf16 = 8 KB), vectorized, pad-aware
    {
        const uint4* src = (const uint4*)(zx + base);   // 512 uint4
#pragma unroll
        for (int it = 0; it < 2; it++) {
            const int i = t + it * 256;                  // chunk of 8 bf16
            const int r = i >> 4, c = (i & 15) * 8;
            *(uint4*)&xs[r][c] = src[i];
        }
    }
    __syncthreads();

    // --- phase A: wave wv computes h1 cols [wv*128, wv*128+128)
    {
        f32x4 acc[2][8];
#pragma unroll
        for (int mt = 0; mt < 2; mt++)
#pragma unroll
            for (int nt = 0; nt < 8; nt++) acc[mt][nt] = (f32x4){0.f, 0.f, 0.f, 0.f};

#pragma unroll
        for (int kk = 0; kk < 4; kk++) {
            const int k0 = kk * 32 + quad * 8;
            const s16x8 a0 = *(const s16x8*)&xs[col][k0];
            const s16x8 a1 = *(const s16x8*)&xs[16 + col][k0];
#pragma unroll
            for (int nt = 0; nt < 8; nt++) {
                const int n = wv * 128 + nt * 16 + col;
                const s16x8 b = *(const s16x8*)&w1t[n * DD + k0];
                acc[0][nt] = __builtin_amdgcn_mfma_f32_16x16x32_bf16(a0, b, acc[0][nt], 0, 0, 0);
                acc[1][nt] = __builtin_amdgcn_mfma_f32_16x16x32_bf16(a1, b, acc[1][nt], 0, 0, 0);
            }
        }
#pragma unroll
        for (int nt = 0; nt < 8; nt++) {
            const int n = wv * 128 + nt * 16 + col;
            const float bias = b1[n];
#pragma unroll
            for (int r = 0; r < 4; r++) {
                const int row = quad * 4 + r;
                h1[row][n]      = __float2bfloat16(fmaxf(acc[0][nt][r] + bias, 0.f));
                h1[16 + row][n] = __float2bfloat16(fmaxf(acc[1][nt][r] + bias, 0.f));
            }
        }
    }
    __syncthreads();

    // --- phase B: wave wv computes u cols [wv*32, wv*32+32)
    {
        f32x4 acc[2][2];
#pragma unroll
        for (int mt = 0; mt < 2; mt++)
#pragma unroll
            for (int nt = 0; nt < 2; nt++) acc[mt][nt] = (f32x4){0.f, 0.f, 0.f, 0.f};

#pragma unroll 4
        for (int kk = 0; kk < 16; kk++) {
            const int k0 = kk * 32 + quad * 8;
            const s16x8 a0 = *(const s16x8*)&h1[col][k0];
            const s16x8 a1 = *(const s16x8*)&h1[16 + col][k0];
#pragma unroll
            for (int nt = 0; nt < 2; nt++) {
                const int n = wv * 32 + nt * 16 + col;
                const s16x8 b = *(const s16x8*)&w2t[n * HIDD + k0];
                acc[0][nt] = __builtin_amdgcn_mfma_f32_16x16x32_bf16(a0, b, acc[0][nt], 0, 0, 0);
                acc[1][nt] = __builtin_amdgcn_mfma_f32_16x16x32_bf16(a1, b, acc[1][nt], 0, 0, 0);
            }
        }
        __syncthreads();   // all waves done reading h1; safe to overwrite as u

        float* u = (float*)&h1[0][0];   // [32][128]
#pragma unroll
        for (int mt = 0; mt < 2; mt++)
#pragma unroll
            for (int nt = 0; nt < 2; nt++) {
                const int n = wv * 32 + nt * 16 + col;
                const float bias = b2[n];
#pragma unroll
                for (int r = 0; r < 4; r++) {
                    const int row = mt * 16 + quad * 4 + r;
                    u[row * DD + n] = acc[mt][nt][r] + bias + __bfloat162float(xs[row][n]);
                }
            }
    }
    __syncthreads();

    // --- LayerNorm per row, write bf16 in-place
    {
        const float* u = (const float*)&h1[0][0];
        for (int r = wv; r < 32; r += 4) {
            const float a0 = u[r * DD + lane], a1 = u[r * DD + lane + 64];
            const float s  = wave_sum(a0 + a1);
            const float sq = wave_sum(a0 * a0 + a1 * a1);
            const float mean = s * (1.0f / DD);
            const float var  = sq * (1.0f / DD) - mean * mean;
            const float inv  = rsqrtf(var + 1e-5f);
            zx[base + r * DD + lane]      = __float2bfloat16((a0 - mean) * inv * lng[lane] + lnb[lane]);
            zx[base + r * DD + lane + 64] = __float2bfloat16((a1 - mean) * inv * lng[lane + 64] + lnb[lane + 64]);
        }
    }
}

// ---------------------------------------------------------------------------
// Kernel 4: fuse self + neighborhood mean, fea2node, gelu, residual, LN -> out
// ---------------------------------------------------------------------------
__global__ __launch_bounds__(128)
void k4_fuse(const bf16* __restrict__ zx, const float* __restrict__ nhs,
             const float* __restrict__ fw, const float* __restrict__ fb,
             const float* __restrict__ lng, const float* __restrict__ lnb,
             float* __restrict__ out)
{
    __shared__ float f[2 * DD];
    __shared__ float red[4];
    const int d = threadIdx.x;
    const int node = blockIdx.x;
    const bf16* xr = zx + node * KK * DD;

    float nb = 0.f;
#pragma unroll
    for (int i = 0; i < KK - 1; i++) nb += __bfloat162float(xr[i * DD + d]);
    f[d] = __bfloat162float(xr[(KK - 1) * DD + d]);
    f[DD + d] = nb * (1.0f / (KK - 1));
    __syncthreads();

    float a = fb[d];
#pragma unroll 4
    for (int c = 0; c < 2 * DD; c++) a += f[c] * fw[c * DD + d];
    const float y = geluf(a) + nhs[(node * KK + KK - 1) * DD + d];

    float s = y, sq = y * y;
#pragma unroll
    for (int o = 32; o > 0; o >>= 1) {
        s += __shfl_down(s, o);
        sq += __shfl_down(sq, o);
    }
    const int wid = d >> 6, lane = d & 63;
    if (lane == 0) { red[wid] = s; red[2 + wid] = sq; }
    __syncthreads();
    const float ts = red[0] + red[1], tsq = red[2] + red[3];
    const float mean = ts * (1.0f / DD);
    const float var = tsq * (1.0f / DD) - mean * mean;
    const float inv = rsqrtf(var + 1e-5f);
    out[node * DD + d] = (y - mean) * inv * lng[d] + lnb[d];
}

// ---------------------------------------------------------------------------
extern "C" void kernel_launch(void* const* d_in, const int* in_sizes, int n_in,
                              void* d_out, int out_size, void* d_ws, size_t ws_size,
                              hipStream_t stream)
{
    const float* nhs   = (const float*)d_in[0];
    const float* t     = (const float*)d_in[1];
    const float* tnow  = (const float*)d_in[2];
    const float* ef    = (const float*)d_in[3];
    const float* freq  = (const float*)d_in[4];
    const float* phase = (const float*)d_in[5];
    const float* ew    = (const float*)d_in[6];
    const float* eb    = (const float*)d_in[7];
    const float* wq    = (const float*)d_in[8];
    const float* wk    = (const float*)d_in[9];
    const float* wv    = (const float*)d_in[10];
    const float* wqs   = (const float*)d_in[11];
    const float* afw   = (const float*)d_in[12];
    const float* afb   = (const float*)d_in[13];
    const float* alng  = (const float*)d_in[14];
    const float* alnb  = (const float*)d_in[15];
    const float* w1    = (const float*)d_in[16];
    const float* b1    = (const float*)d_in[17];
    const float* w2    = (const float*)d_in[18];
    const float* b2    = (const float*)d_in[19];
    const float* flng  = (const float*)d_in[20];
    const float* flnb  = (const float*)d_in[21];
    const float* fw    = (const float*)d_in[22];
    const float* fb    = (const float*)d_in[23];
    const float* olng  = (const float*)d_in[24];
    const float* olnb  = (const float*)d_in[25];
    float* out = (float*)d_out;

    bf16* zx  = (bf16*)d_ws;                                   // 102,400,000 B
    bf16* w1t = (bf16*)((char*)d_ws + (size_t)RTOT * DD * 2);  // +131072 B  [512][128]
    bf16* w2t = w1t + HIDD * DD;                               // +131072 B  [128][512]
    bf16* aw  = w2t + DD * HIDD;                               // +196608 B  6x[128][128]
    bf16* ewt = aw + 5 * DD * DD;                              // last matrix of aw

    k0_conv<<<dim3(2 * HIDD * DD / 256), dim3(256), 0, stream>>>(w1, w2, w1t, w2t);
    k0b_conv<<<dim3(6 * DD * DD / 256), dim3(256), 0, stream>>>(wq, wk, wv, wqs, afw, ew, aw);
    k1_msg<<<dim3(RTOT / 32), dim3(256), 0, stream>>>(nhs, t, tnow, ef, freq, phase, ewt, eb, zx);
    k2_attn<<<dim3(N_NODES), dim3(256), 0, stream>>>(zx, aw, afb, alng, alnb);
    k3_ffn<<<dim3(RTOT / 32), dim3(256), 0, stream>>>(zx, w1t, b1, w2t, b2, flng, flnb);
    k4_fuse<<<dim3(N_NODES), dim3(128), 0, stream>>>(zx, nhs, fw, fb, olng, olnb, out);
}